// Round 2
// baseline (4174.512 us; speedup 1.0000x reference)
//
#include <hip/hip_runtime.h>
#include <math.h>

#define BN   16384
#define NN   13
#define NC   26
#define VOC  10000
#define E    64
#define LAYERS 3
#define H    2
#define F    39
#define D    32
#define EP   66   // LDS row pad for [F][E] tiles (float2-aligned, conflict-benign)
#define SP   41   // LDS row pad for score tiles

__global__ __launch_bounds__(256) void autoint_kernel(
    const float* __restrict__ num, const int* __restrict__ cat,
    const float* __restrict__ Wnum, const float* __restrict__ bnum,
    const float* __restrict__ tabs,
    const float* __restrict__ WQ, const float* __restrict__ WK,
    const float* __restrict__ WV, const float* __restrict__ WO,
    const float* __restrict__ WR,
    const float* __restrict__ Wf, const float* __restrict__ bf,
    float* __restrict__ out)
{
    __shared__ float xs[F][EP];
    __shared__ float Qs[F][EP];   // doubles as attention-output buffer
    __shared__ float Ks[F][EP];
    __shared__ float Vs[F][EP];
    __shared__ float Ss[H][F][SP];
    __shared__ float red[4];

    const int tid  = threadIdx.x;
    const int lane = tid & 63;
    const int w    = tid >> 6;
    const int s    = blockIdx.x;

    // ---------------- embedding ----------------
    for (int f = w; f < NN; f += 4) {
        float nv = num[s * NN + f];
        xs[f][lane] = nv * Wnum[f * E + lane] + bnum[f * E + lane];
    }
    for (int c = w; c < NC; c += 4) {
        int idx = cat[s * NC + c];
        xs[NN + c][lane] = tabs[((size_t)c * VOC + idx) * E + lane];
    }
    __syncthreads();

    const int h = lane >> 5;
    const int t = lane & 31;
    const float scale = 0.17677669529663687f; // 1/sqrt(32)

    for (int l = 0; l < LAYERS; ++l) {
        // ---------------- Q, K, V projections ----------------
        for (int m = 0; m < 3; ++m) {
            const float* Wm = (m == 0) ? (WQ + l*E*E) : (m == 1) ? (WK + l*E*E) : (WV + l*E*E);
            float (*dst)[EP] = (m == 0) ? Qs : (m == 1) ? Ks : Vs;
            float wr[E];
            const float4* w4 = (const float4*)(Wm + lane * E);
            #pragma unroll
            for (int j = 0; j < 16; ++j) ((float4*)wr)[j] = w4[j];
            for (int f = w; f < F; f += 4) {
                float acc = 0.f;
                #pragma unroll
                for (int j = 0; j < 32; ++j) {
                    float2 xv = *(const float2*)&xs[f][2 * j];
                    acc += xv.x * wr[2*j] + xv.y * wr[2*j + 1];
                }
                dst[f][lane] = acc;
            }
        }
        __syncthreads();

        // ---------------- scores = QK^T / sqrt(D) ----------------
        for (int q = w; q < F; q += 4) {
            float s0 = 0.f, s1 = 0.f;
            #pragma unroll
            for (int dd = 0; dd < 16; ++dd) {
                float2 qv = *(const float2*)&Qs[q][h * D + 2 * dd];
                float2 k0 = *(const float2*)&Ks[t][h * D + 2 * dd];
                s0 += qv.x * k0.x + qv.y * k0.y;
                if (t < 7) {
                    float2 k1 = *(const float2*)&Ks[t + 32][h * D + 2 * dd];
                    s1 += qv.x * k1.x + qv.y * k1.y;
                }
            }
            Ss[h][q][t] = s0 * scale;
            if (t < 7) Ss[h][q][t + 32] = s1 * scale;
        }
        __syncthreads();

        // ---------------- softmax over k ----------------
        {
            int p = w * 20 + lane;
            if (lane < 20 && p < H * F) {
                int hh = p / F, qq = p % F;
                float m = -1e30f;
                for (int k = 0; k < F; ++k) m = fmaxf(m, Ss[hh][qq][k]);
                float sum = 0.f;
                for (int k = 0; k < F; ++k) {
                    float e = __expf(Ss[hh][qq][k] - m);
                    Ss[hh][qq][k] = e;
                    sum += e;
                }
                float inv = 1.f / sum;
                for (int k = 0; k < F; ++k) Ss[hh][qq][k] *= inv;
            }
        }
        __syncthreads();

        // ---------------- attn @ V  (writes into Qs, now dead) ----------------
        for (int q = w; q < F; q += 4) {
            float acc = 0.f;
            for (int k = 0; k < F; ++k)
                acc += Ss[h][q][k] * Vs[k][lane];
            Qs[q][lane] = acc;
        }
        __syncthreads();

        // ---------------- out @ WO^T + x @ WRes^T ----------------
        float accr[10];
        {
            float wr[E];
            const float4* w4 = (const float4*)(WO + l*E*E + lane * E);
            #pragma unroll
            for (int j = 0; j < 16; ++j) ((float4*)wr)[j] = w4[j];
            int n = 0;
            for (int f = w; f < F; f += 4, ++n) {
                float a = 0.f;
                #pragma unroll
                for (int j = 0; j < 32; ++j) {
                    float2 ov = *(const float2*)&Qs[f][2 * j];
                    a += ov.x * wr[2*j] + ov.y * wr[2*j + 1];
                }
                accr[n] = a;
            }
            const float4* w4r = (const float4*)(WR + l*E*E + lane * E);
            #pragma unroll
            for (int j = 0; j < 16; ++j) ((float4*)wr)[j] = w4r[j];
            n = 0;
            for (int f = w; f < F; f += 4, ++n) {
                float a = accr[n];
                #pragma unroll
                for (int j = 0; j < 32; ++j) {
                    float2 xv = *(const float2*)&xs[f][2 * j];
                    a += xv.x * wr[2*j] + xv.y * wr[2*j + 1];
                }
                accr[n] = a;
            }
        }
        __syncthreads();
        {
            int n = 0;
            for (int f = w; f < F; f += 4, ++n) xs[f][lane] = accr[n];
        }
        __syncthreads();
    }

    // ---------------- final linear + sigmoid ----------------
    float p = 0.f;
    for (int idx = tid; idx < F * E; idx += 256)
        p += xs[idx >> 6][idx & 63] * Wf[idx];
    #pragma unroll
    for (int off = 32; off > 0; off >>= 1)
        p += __shfl_down(p, off, 64);
    if (lane == 0) red[w] = p;
    __syncthreads();
    if (tid == 0) {
        float logit = red[0] + red[1] + red[2] + red[3] + bf[0];
        out[s] = 1.f / (1.f + __expf(-logit));
    }
}

extern "C" void kernel_launch(void* const* d_in, const int* in_sizes, int n_in,
                              void* d_out, int out_size, void* d_ws, size_t ws_size,
                              hipStream_t stream) {
    autoint_kernel<<<BN, 256, 0, stream>>>(
        (const float*)d_in[0], (const int*)d_in[1],
        (const float*)d_in[2], (const float*)d_in[3],
        (const float*)d_in[4],
        (const float*)d_in[5], (const float*)d_in[6], (const float*)d_in[7],
        (const float*)d_in[8], (const float*)d_in[9],
        (const float*)d_in[10], (const float*)d_in[11],
        (float*)d_out);
}

// Round 3
// 509.457 us; speedup vs baseline: 8.1940x; 8.1940x over previous
//
#include <hip/hip_runtime.h>
#include <math.h>

#define NN 13
#define NC 26
#define VOC 10000
#define E 64
#define LAYERS 3
#define F 39
#define P 72   // ushort pitch: 144B rows -> uniform (conflict-free) b128/b64 LDS patterns

typedef float f32x4 __attribute__((ext_vector_type(4)));
typedef short s16x8 __attribute__((ext_vector_type(8)));

__device__ __forceinline__ ushort f2bf(float f) {
    uint u = __builtin_bit_cast(uint, f);
    u = (u + 0x7fffu + ((u >> 16) & 1u)) >> 16;   // RNE
    return (ushort)u;
}
__device__ __forceinline__ float bf2f(ushort h) {
    uint u = ((uint)h) << 16;
    return __builtin_bit_cast(float, u);
}
__device__ __forceinline__ void pack4(ushort* dst, f32x4 v) {
    ushort4 p;
    p.x = f2bf(v[0]); p.y = f2bf(v[1]); p.z = f2bf(v[2]); p.w = f2bf(v[3]);
    *(ushort4*)dst = p;
}

// ---- one-shot fp32 -> bf16 weight conversion into d_ws ----
// ws layout (ushort): [WQ 3*4096][WK 3*4096][WV 3*4096][WO 3*4096][WR 3*4096]
__global__ void cvt_weights(const float* __restrict__ wq, const float* __restrict__ wk,
                            const float* __restrict__ wv, const float* __restrict__ wo,
                            const float* __restrict__ wr, ushort* __restrict__ outw) {
    int i = blockIdx.x * 256 + threadIdx.x;
    if (i >= 5 * 3 * 4096) return;
    int m = i / 12288, jj = i - m * 12288;
    const float* src = (m == 0) ? wq : (m == 1) ? wk : (m == 2) ? wv : (m == 3) ? wo : wr;
    outw[i] = f2bf(src[jj]);
}

__global__ __launch_bounds__(64) void autoint_mfma(
    const float* __restrict__ num, const int* __restrict__ cat,
    const float* __restrict__ Wnum, const float* __restrict__ bnum,
    const float* __restrict__ tabs, const ushort* __restrict__ wsw,
    const float* __restrict__ Wf, const float* __restrict__ bfin,
    float* __restrict__ out)
{
    __shared__ __align__(16) ushort smem[14976];
    ushort* xs = smem;           // [48][72] x (bf16, row-major [field][dim])
    ushort* Qs = smem + 3456;    // [48][72] Q row-major [field][dim]; later aliased as Pt [q][key]
    ushort* Ks = smem + 6912;    // [48][72] K row-major [field][dim]; later aliased as Ot [q][dim]
    ushort* Vt = smem + 10368;   // [64][72] V transposed [dim][key]
    ushort* Pt = Qs;
    ushort* Ot = Ks;

    const int l = threadIdx.x;
    const int j = l & 15;
    const int g = l >> 4;
    const int s = blockIdx.x;

    // zero Vt pad key-columns 48..63 (never written by projections)
    {
        ushort4 z; z.x = z.y = z.z = z.w = 0;
        #pragma unroll
        for (int i = 0; i < 4; ++i) {
            int t = l + 64 * i;           // 256 quad-writes: 64 rows x 4 quads
            int r = t >> 2, q = t & 3;
            *(ushort4*)&Vt[r * P + 48 + 4 * q] = z;
        }
    }

    // ---------------- embedding ----------------
    for (int f = 0; f < NN; ++f) {
        float v = num[s * NN + f];
        xs[f * P + l] = f2bf(v * Wnum[f * E + l] + bnum[f * E + l]);
    }
    for (int c = 0; c < NC; ++c) {
        int idx = cat[s * NC + c];
        xs[(NN + c) * P + l] = f2bf(tabs[((size_t)(c * VOC + idx)) * E + l]);
    }
    for (int r = F; r < 48; ++r) xs[r * P + l] = 0;
    __syncthreads();

    const float scale = 0.17677669529663687f; // 1/sqrt(32)

    for (int l3 = 0; l3 < LAYERS; ++l3) {
        const ushort* wq = wsw + 0 * 12288 + l3 * 4096;
        const ushort* wk = wsw + 1 * 12288 + l3 * 4096;
        const ushort* wv = wsw + 2 * 12288 + l3 * 4096;
        const ushort* wo = wsw + 3 * 12288 + l3 * 4096;
        const ushort* wr = wsw + 4 * 12288 + l3 * 4096;

        // x fragments: serve as B (x^T) for Q/K/WR-swapped matmuls and A for V
        s16x8 xf[3][2];
        #pragma unroll
        for (int nt = 0; nt < 3; ++nt)
            #pragma unroll
            for (int kt = 0; kt < 2; ++kt)
                xf[nt][kt] = *(const s16x8*)&xs[(j + 16 * nt) * P + 8 * g + 32 * kt];

        // ---- Q^T = WQ @ x^T, K^T = WK @ x^T (D rows = outdim, cols = field) ----
        {
            f32x4 qa[4][3], ka[4][3];
            #pragma unroll
            for (int mt = 0; mt < 4; ++mt)
                #pragma unroll
                for (int nt = 0; nt < 3; ++nt) { qa[mt][nt] = (f32x4)0.f; ka[mt][nt] = (f32x4)0.f; }
            #pragma unroll
            for (int kt = 0; kt < 2; ++kt)
                #pragma unroll
                for (int mt = 0; mt < 4; ++mt) {
                    s16x8 aq = *(const s16x8*)&wq[(j + 16 * mt) * E + 8 * g + 32 * kt];
                    s16x8 ak = *(const s16x8*)&wk[(j + 16 * mt) * E + 8 * g + 32 * kt];
                    #pragma unroll
                    for (int nt = 0; nt < 3; ++nt) {
                        qa[mt][nt] = __builtin_amdgcn_mfma_f32_16x16x32_bf16(aq, xf[nt][kt], qa[mt][nt], 0, 0, 0);
                        ka[mt][nt] = __builtin_amdgcn_mfma_f32_16x16x32_bf16(ak, xf[nt][kt], ka[mt][nt], 0, 0, 0);
                    }
                }
            #pragma unroll
            for (int mt = 0; mt < 4; ++mt)
                #pragma unroll
                for (int nt = 0; nt < 3; ++nt) {
                    pack4(&Qs[(j + 16 * nt) * P + 16 * mt + 4 * g], qa[mt][nt]); // Q[field][dim]
                    pack4(&Ks[(j + 16 * nt) * P + 16 * mt + 4 * g], ka[mt][nt]); // K[field][dim]
                }
        }
        // ---- V = x @ WV^T (D rows = field/key, cols = dim) -> store transposed Vt[dim][key] ----
        {
            f32x4 va[3][4];
            #pragma unroll
            for (int mt = 0; mt < 3; ++mt)
                #pragma unroll
                for (int nt = 0; nt < 4; ++nt) va[mt][nt] = (f32x4)0.f;
            #pragma unroll
            for (int kt = 0; kt < 2; ++kt)
                #pragma unroll
                for (int nt = 0; nt < 4; ++nt) {
                    s16x8 bv = *(const s16x8*)&wv[(j + 16 * nt) * E + 8 * g + 32 * kt];
                    #pragma unroll
                    for (int mt = 0; mt < 3; ++mt)
                        va[mt][nt] = __builtin_amdgcn_mfma_f32_16x16x32_bf16(xf[mt][kt], bv, va[mt][nt], 0, 0, 0);
                }
            #pragma unroll
            for (int mt = 0; mt < 3; ++mt)
                #pragma unroll
                for (int nt = 0; nt < 4; ++nt)
                    pack4(&Vt[(j + 16 * nt) * P + 16 * mt + 4 * g], va[mt][nt]); // Vt[dim][key]
        }
        __syncthreads();

        // ---- scores, both heads: S^T = K_h @ Q_h^T  (D rows = key, cols = query) ----
        f32x4 sc[2][3][3];
        #pragma unroll
        for (int h = 0; h < 2; ++h) {
            s16x8 kA[3], qB[3];
            #pragma unroll
            for (int t = 0; t < 3; ++t) {
                kA[t] = *(const s16x8*)&Ks[(j + 16 * t) * P + 32 * h + 8 * g];
                qB[t] = *(const s16x8*)&Qs[(j + 16 * t) * P + 32 * h + 8 * g];
            }
            #pragma unroll
            for (int mt = 0; mt < 3; ++mt)
                #pragma unroll
                for (int nt = 0; nt < 3; ++nt)
                    sc[h][mt][nt] = __builtin_amdgcn_mfma_f32_16x16x32_bf16(kA[mt], qB[nt], (f32x4)0.f, 0, 0, 0);
        }

        // ---- softmax over keys, in-register (lane owns 12 keys per (h,nt); group = lanes {j,j+16,j+32,j+48}) ----
        #pragma unroll
        for (int h = 0; h < 2; ++h)
            #pragma unroll
            for (int nt = 0; nt < 3; ++nt) {
                float mx = -1e30f;
                #pragma unroll
                for (int mt = 0; mt < 3; ++mt)
                    #pragma unroll
                    for (int r = 0; r < 4; ++r) {
                        int key = 16 * mt + 4 * g + r;
                        float v = (key < F) ? sc[h][mt][nt][r] * scale : -1e30f;
                        sc[h][mt][nt][r] = v;
                        mx = fmaxf(mx, v);
                    }
                mx = fmaxf(mx, __shfl_xor(mx, 16));
                mx = fmaxf(mx, __shfl_xor(mx, 32));
                float sum = 0.f;
                #pragma unroll
                for (int mt = 0; mt < 3; ++mt)
                    #pragma unroll
                    for (int r = 0; r < 4; ++r) {
                        float e = __expf(sc[h][mt][nt][r] - mx);
                        sc[h][mt][nt][r] = e;
                        sum += e;
                    }
                sum += __shfl_xor(sum, 16);
                sum += __shfl_xor(sum, 32);
                float inv = 1.f / sum;
                #pragma unroll
                for (int mt = 0; mt < 3; ++mt)
                    #pragma unroll
                    for (int r = 0; r < 4; ++r) sc[h][mt][nt][r] *= inv;
            }
        __syncthreads();  // Qs/Ks fully consumed -> reusable as Pt/Ot

        // ---- per head: write Pt[q][key] (pad keys 48..63 = 0), PV: out^T = V_h^T @ P^T, write Ot[q][dim] ----
        #pragma unroll
        for (int h = 0; h < 2; ++h) {
            #pragma unroll
            for (int nt = 0; nt < 3; ++nt) {
                #pragma unroll
                for (int mt = 0; mt < 3; ++mt)
                    pack4(&Pt[(16 * nt + j) * P + 16 * mt + 4 * g], sc[h][mt][nt]);
                ushort4 z; z.x = z.y = z.z = z.w = 0;
                *(ushort4*)&Pt[(16 * nt + j) * P + 48 + 4 * g] = z;
            }
            __syncthreads();
            f32x4 oa[2][3];
            #pragma unroll
            for (int md = 0; md < 2; ++md)
                #pragma unroll
                for (int nt = 0; nt < 3; ++nt) oa[md][nt] = (f32x4)0.f;
            #pragma unroll
            for (int kt = 0; kt < 2; ++kt) {
                s16x8 pb[3];
                #pragma unroll
                for (int nt = 0; nt < 3; ++nt)
                    pb[nt] = *(const s16x8*)&Pt[(j + 16 * nt) * P + 8 * g + 32 * kt];
                #pragma unroll
                for (int md = 0; md < 2; ++md) {
                    s16x8 va = *(const s16x8*)&Vt[(j + 16 * (2 * h + md)) * P + 8 * g + 32 * kt];
                    #pragma unroll
                    for (int nt = 0; nt < 3; ++nt)
                        oa[md][nt] = __builtin_amdgcn_mfma_f32_16x16x32_bf16(va, pb[nt], oa[md][nt], 0, 0, 0);
                }
            }
            #pragma unroll
            for (int md = 0; md < 2; ++md)
                #pragma unroll
                for (int nt = 0; nt < 3; ++nt)
                    pack4(&Ot[(16 * nt + j) * P + 32 * h + 16 * md + 4 * g], oa[md][nt]);
            __syncthreads();
        }

        // ---- next x^T = WO @ out^T + WR @ x^T -> write xs[field][dim] ----
        {
            f32x4 na[4][3];
            #pragma unroll
            for (int mt = 0; mt < 4; ++mt)
                #pragma unroll
                for (int nt = 0; nt < 3; ++nt) na[mt][nt] = (f32x4)0.f;
            #pragma unroll
            for (int kt = 0; kt < 2; ++kt) {
                s16x8 ob[3];
                #pragma unroll
                for (int nt = 0; nt < 3; ++nt)
                    ob[nt] = *(const s16x8*)&Ot[(j + 16 * nt) * P + 8 * g + 32 * kt];
                #pragma unroll
                for (int mt = 0; mt < 4; ++mt) {
                    s16x8 ao = *(const s16x8*)&wo[(j + 16 * mt) * E + 8 * g + 32 * kt];
                    s16x8 ar = *(const s16x8*)&wr[(j + 16 * mt) * E + 8 * g + 32 * kt];
                    #pragma unroll
                    for (int nt = 0; nt < 3; ++nt) {
                        na[mt][nt] = __builtin_amdgcn_mfma_f32_16x16x32_bf16(ao, ob[nt], na[mt][nt], 0, 0, 0);
                        na[mt][nt] = __builtin_amdgcn_mfma_f32_16x16x32_bf16(ar, xf[nt][kt], na[mt][nt], 0, 0, 0);
                    }
                }
            }
            __syncthreads();
            #pragma unroll
            for (int mt = 0; mt < 4; ++mt)
                #pragma unroll
                for (int nt = 0; nt < 3; ++nt)
                    pack4(&xs[(16 * nt + j) * P + 16 * mt + 4 * g], na[mt][nt]);
        }
        __syncthreads();
    }

    // ---------------- final linear + sigmoid ----------------
    float acc = 0.f;
    for (int f = 0; f < F; ++f)
        acc += bf2f(xs[f * P + l]) * Wf[f * E + l];
    #pragma unroll
    for (int off = 32; off > 0; off >>= 1) acc += __shfl_down(acc, off);
    if (l == 0) out[s] = 1.f / (1.f + __expf(-(acc + bfin[0])));
}

extern "C" void kernel_launch(void* const* d_in, const int* in_sizes, int n_in,
                              void* d_out, int out_size, void* d_ws, size_t ws_size,
                              hipStream_t stream) {
    ushort* wsb = (ushort*)d_ws;   // 61440 ushorts = 122880 B of scratch
    cvt_weights<<<240, 256, 0, stream>>>(
        (const float*)d_in[5], (const float*)d_in[6], (const float*)d_in[7],
        (const float*)d_in[8], (const float*)d_in[9], wsb);
    autoint_mfma<<<16384, 64, 0, stream>>>(
        (const float*)d_in[0], (const int*)d_in[1],
        (const float*)d_in[2], (const float*)d_in[3],
        (const float*)d_in[4], wsb,
        (const float*)d_in[10], (const float*)d_in[11],
        (float*)d_out);
}

// Round 4
// 268.558 us; speedup vs baseline: 15.5442x; 1.8970x over previous
//
#include <hip/hip_runtime.h>
#include <hip/hip_bf16.h>
#include <math.h>

#define NN 13
#define NC 26
#define VOC 10000
#define E 64
#define LAYERS 3
#define F 39
#define P 72   // ushort pitch (144B rows)

typedef float f32x4 __attribute__((ext_vector_type(4)));
typedef short s16x8 __attribute__((ext_vector_type(8)));

__device__ __forceinline__ ushort f2bf_rne(float f) {   // weight-cvt kernel only
    uint u = __builtin_bit_cast(uint, f);
    u = (u + 0x7fffu + ((u >> 16) & 1u)) >> 16;
    return (ushort)u;
}
__device__ __forceinline__ ushort fb(float f) {          // hot path: fuses to v_cvt_pk_bf16_f32
    return __builtin_bit_cast(ushort, __float2bfloat16(f));
}
__device__ __forceinline__ void pack4(ushort* dst, f32x4 v) {
    ushort4 p;
    p.x = fb(v[0]); p.y = fb(v[1]); p.z = fb(v[2]); p.w = fb(v[3]);
    *(ushort4*)dst = p;
}

// ---- one-shot fp32 -> bf16 weight conversion into d_ws ----
// ws layout (ushort): [WQ 3*4096][WK 3*4096][WV 3*4096][WO 3*4096][WR 3*4096]
__global__ void cvt_weights(const float* __restrict__ wq, const float* __restrict__ wk,
                            const float* __restrict__ wv, const float* __restrict__ wo,
                            const float* __restrict__ wr, ushort* __restrict__ outw) {
    int i = blockIdx.x * 256 + threadIdx.x;
    if (i >= 5 * 3 * 4096) return;
    int m = i / 12288, jj = i - m * 12288;
    const float* src = (m == 0) ? wq : (m == 1) ? wk : (m == 2) ? wv : (m == 3) ? wo : wr;
    outw[i] = f2bf_rne(src[jj]);
}

__global__ __launch_bounds__(64, 2) void autoint_mfma(
    const float* __restrict__ num, const int* __restrict__ cat,
    const float* __restrict__ Wnum, const float* __restrict__ bnum,
    const float* __restrict__ tabs, const ushort* __restrict__ wsw,
    const float* __restrict__ Wf, const float* __restrict__ bfin,
    float* __restrict__ out)
{
    __shared__ __align__(16) ushort smem[8064];
    ushort* S  = smem;          // [48][72] time-shared staging: x / Q / K / Pt / Ot / x'
    ushort* Vt = smem + 3456;   // [64][72] V transposed [dim][key], persistent within layer

    const int l = threadIdx.x;
    const int j = l & 15;
    const int g = l >> 4;
    const int s = blockIdx.x;

    ushort4 z4; z4.x = z4.y = z4.z = z4.w = 0;
    // zero Vt pad key-columns 48..63 (never written by projections, stays zero)
    #pragma unroll
    for (int i = 0; i < 4; ++i) {
        int t = l + 64 * i;
        int r = t >> 2, q = t & 3;
        *(ushort4*)&Vt[r * P + 48 + 4 * q] = z4;
    }

    // ---------------- embedding into S ----------------
    for (int f = 0; f < NN; ++f) {
        float v = num[s * NN + f];
        S[f * P + l] = fb(v * Wnum[f * E + l] + bnum[f * E + l]);
    }
    for (int c = 0; c < NC; ++c) {
        int idx = cat[s * NC + c];
        S[(NN + c) * P + l] = fb(tabs[((size_t)(c * VOC + idx)) * E + l]);
    }
    for (int r = F; r < 48; ++r) S[r * P + l] = 0;
    __syncthreads();

    // x fragments in registers (whole x, distributed): row j+16nt, dims 8g..8g+7 (+32kt)
    s16x8 xf[3][2];
    #pragma unroll
    for (int nt = 0; nt < 3; ++nt)
        #pragma unroll
        for (int kt = 0; kt < 2; ++kt)
            xf[nt][kt] = *(const s16x8*)&S[(j + 16 * nt) * P + 8 * g + 32 * kt];

    const float scale = 0.17677669529663687f; // 1/sqrt(32)

    for (int l3 = 0; l3 < LAYERS; ++l3) {
        const ushort* wq = wsw + 0 * 12288 + l3 * 4096;
        const ushort* wk = wsw + 1 * 12288 + l3 * 4096;
        const ushort* wv = wsw + 2 * 12288 + l3 * 4096;
        const ushort* wo = wsw + 3 * 12288 + l3 * 4096;
        const ushort* wr = wsw + 4 * 12288 + l3 * 4096;

        // ---- Q^T = WQ @ x^T -> stage in S -> qB frags (held in regs, both heads) ----
        s16x8 qB[2][3];
        {
            f32x4 qa[4][3];
            #pragma unroll
            for (int mt = 0; mt < 4; ++mt)
                #pragma unroll
                for (int nt = 0; nt < 3; ++nt) qa[mt][nt] = (f32x4)0.f;
            #pragma unroll
            for (int kt = 0; kt < 2; ++kt)
                #pragma unroll
                for (int mt = 0; mt < 4; ++mt) {
                    s16x8 aq = *(const s16x8*)&wq[(j + 16 * mt) * E + 8 * g + 32 * kt];
                    #pragma unroll
                    for (int nt = 0; nt < 3; ++nt)
                        qa[mt][nt] = __builtin_amdgcn_mfma_f32_16x16x32_bf16(aq, xf[nt][kt], qa[mt][nt], 0, 0, 0);
                }
            __syncthreads();   // xf reads done (and prior-phase readers)
            #pragma unroll
            for (int mt = 0; mt < 4; ++mt)
                #pragma unroll
                for (int nt = 0; nt < 3; ++nt)
                    pack4(&S[(j + 16 * nt) * P + 16 * mt + 4 * g], qa[mt][nt]);  // Q[field][dim]
            __syncthreads();
            #pragma unroll
            for (int h = 0; h < 2; ++h)
                #pragma unroll
                for (int t = 0; t < 3; ++t)
                    qB[h][t] = *(const s16x8*)&S[(j + 16 * t) * P + 32 * h + 8 * g];
            __syncthreads();
        }

        // ---- K^T = WK @ x^T -> stage in S (overwrites Q) ----
        {
            f32x4 ka[4][3];
            #pragma unroll
            for (int mt = 0; mt < 4; ++mt)
                #pragma unroll
                for (int nt = 0; nt < 3; ++nt) ka[mt][nt] = (f32x4)0.f;
            #pragma unroll
            for (int kt = 0; kt < 2; ++kt)
                #pragma unroll
                for (int mt = 0; mt < 4; ++mt) {
                    s16x8 ak = *(const s16x8*)&wk[(j + 16 * mt) * E + 8 * g + 32 * kt];
                    #pragma unroll
                    for (int nt = 0; nt < 3; ++nt)
                        ka[mt][nt] = __builtin_amdgcn_mfma_f32_16x16x32_bf16(ak, xf[nt][kt], ka[mt][nt], 0, 0, 0);
                }
            #pragma unroll
            for (int mt = 0; mt < 4; ++mt)
                #pragma unroll
                for (int nt = 0; nt < 3; ++nt)
                    pack4(&S[(j + 16 * nt) * P + 16 * mt + 4 * g], ka[mt][nt]);  // K[field][dim]
            __syncthreads();
        }

        // ---- V = x @ WV^T -> Vt[dim][key] (separate buffer) ----
        {
            f32x4 va[3][4];
            #pragma unroll
            for (int mt = 0; mt < 3; ++mt)
                #pragma unroll
                for (int nt = 0; nt < 4; ++nt) va[mt][nt] = (f32x4)0.f;
            #pragma unroll
            for (int kt = 0; kt < 2; ++kt)
                #pragma unroll
                for (int nt = 0; nt < 4; ++nt) {
                    s16x8 bv = *(const s16x8*)&wv[(j + 16 * nt) * E + 8 * g + 32 * kt];
                    #pragma unroll
                    for (int mt = 0; mt < 3; ++mt)
                        va[mt][nt] = __builtin_amdgcn_mfma_f32_16x16x32_bf16(xf[mt][kt], bv, va[mt][nt], 0, 0, 0);
                }
            #pragma unroll
            for (int mt = 0; mt < 3; ++mt)
                #pragma unroll
                for (int nt = 0; nt < 4; ++nt)
                    pack4(&Vt[(j + 16 * nt) * P + 16 * mt + 4 * g], va[mt][nt]);
        }

        // ---- scores: S^T = K_h @ Q_h^T (kA read per head from S) ----
        f32x4 sc[2][3][3];
        #pragma unroll
        for (int h = 0; h < 2; ++h) {
            s16x8 kA[3];
            #pragma unroll
            for (int t = 0; t < 3; ++t)
                kA[t] = *(const s16x8*)&S[(j + 16 * t) * P + 32 * h + 8 * g];
            #pragma unroll
            for (int mt = 0; mt < 3; ++mt)
                #pragma unroll
                for (int nt = 0; nt < 3; ++nt)
                    sc[h][mt][nt] = __builtin_amdgcn_mfma_f32_16x16x32_bf16(kA[mt], qB[h][nt], (f32x4)0.f, 0, 0, 0);
        }

        // ---- softmax over keys, in-register ----
        #pragma unroll
        for (int h = 0; h < 2; ++h)
            #pragma unroll
            for (int nt = 0; nt < 3; ++nt) {
                float mx = -1e30f;
                #pragma unroll
                for (int mt = 0; mt < 3; ++mt)
                    #pragma unroll
                    for (int r = 0; r < 4; ++r) {
                        int key = 16 * mt + 4 * g + r;
                        float v = (key < F) ? sc[h][mt][nt][r] * scale : -1e30f;
                        sc[h][mt][nt][r] = v;
                        mx = fmaxf(mx, v);
                    }
                mx = fmaxf(mx, __shfl_xor(mx, 16));
                mx = fmaxf(mx, __shfl_xor(mx, 32));
                float sum = 0.f;
                #pragma unroll
                for (int mt = 0; mt < 3; ++mt)
                    #pragma unroll
                    for (int r = 0; r < 4; ++r) {
                        float e = __expf(sc[h][mt][nt][r] - mx);
                        sc[h][mt][nt][r] = e;
                        sum += e;
                    }
                sum += __shfl_xor(sum, 16);
                sum += __shfl_xor(sum, 32);
                float inv = 1.f / sum;
                #pragma unroll
                for (int mt = 0; mt < 3; ++mt)
                    #pragma unroll
                    for (int r = 0; r < 4; ++r) sc[h][mt][nt][r] *= inv;
            }
        __syncthreads();   // kA reads done; S reusable as Pt

        // ---- Pt per head -> pb frags (both heads held in regs) ----
        s16x8 pb[2][2][3];   // [h][kt][nt]
        #pragma unroll
        for (int h = 0; h < 2; ++h) {
            #pragma unroll
            for (int nt = 0; nt < 3; ++nt) {
                #pragma unroll
                for (int mt = 0; mt < 3; ++mt)
                    pack4(&S[(16 * nt + j) * P + 16 * mt + 4 * g], sc[h][mt][nt]);
                *(ushort4*)&S[(16 * nt + j) * P + 48 + 4 * g] = z4;  // zero key-pad 48..63
            }
            __syncthreads();
            #pragma unroll
            for (int kt = 0; kt < 2; ++kt)
                #pragma unroll
                for (int nt = 0; nt < 3; ++nt)
                    pb[h][kt][nt] = *(const s16x8*)&S[(j + 16 * nt) * P + 8 * g + 32 * kt];
            __syncthreads();
        }

        // ---- PV both heads: out^T = V_h^T @ P_h^T ----
        f32x4 oa[2][2][3];   // [h][md][nt]
        #pragma unroll
        for (int h = 0; h < 2; ++h)
            #pragma unroll
            for (int md = 0; md < 2; ++md)
                #pragma unroll
                for (int nt = 0; nt < 3; ++nt) oa[h][md][nt] = (f32x4)0.f;
        #pragma unroll
        for (int kt = 0; kt < 2; ++kt)
            #pragma unroll
            for (int h = 0; h < 2; ++h)
                #pragma unroll
                for (int md = 0; md < 2; ++md) {
                    s16x8 va = *(const s16x8*)&Vt[(j + 16 * (2 * h + md)) * P + 8 * g + 32 * kt];
                    #pragma unroll
                    for (int nt = 0; nt < 3; ++nt)
                        oa[h][md][nt] = __builtin_amdgcn_mfma_f32_16x16x32_bf16(va, pb[h][kt][nt], oa[h][md][nt], 0, 0, 0);
                }
        // Ot[q][dim] -> S
        #pragma unroll
        for (int h = 0; h < 2; ++h)
            #pragma unroll
            for (int md = 0; md < 2; ++md)
                #pragma unroll
                for (int nt = 0; nt < 3; ++nt)
                    pack4(&S[(16 * nt + j) * P + 32 * h + 16 * md + 4 * g], oa[h][md][nt]);
        __syncthreads();

        // ---- next x^T = WO @ out^T + WR @ x^T ----
        {
            f32x4 na[4][3];
            #pragma unroll
            for (int mt = 0; mt < 4; ++mt)
                #pragma unroll
                for (int nt = 0; nt < 3; ++nt) na[mt][nt] = (f32x4)0.f;
            #pragma unroll
            for (int kt = 0; kt < 2; ++kt) {
                s16x8 ob[3];
                #pragma unroll
                for (int nt = 0; nt < 3; ++nt)
                    ob[nt] = *(const s16x8*)&S[(j + 16 * nt) * P + 8 * g + 32 * kt];
                #pragma unroll
                for (int mt = 0; mt < 4; ++mt) {
                    s16x8 ao = *(const s16x8*)&wo[(j + 16 * mt) * E + 8 * g + 32 * kt];
                    s16x8 ar = *(const s16x8*)&wr[(j + 16 * mt) * E + 8 * g + 32 * kt];
                    #pragma unroll
                    for (int nt = 0; nt < 3; ++nt) {
                        na[mt][nt] = __builtin_amdgcn_mfma_f32_16x16x32_bf16(ao, ob[nt], na[mt][nt], 0, 0, 0);
                        na[mt][nt] = __builtin_amdgcn_mfma_f32_16x16x32_bf16(ar, xf[nt][kt], na[mt][nt], 0, 0, 0);
                    }
                }
            }
            __syncthreads();
            #pragma unroll
            for (int mt = 0; mt < 4; ++mt)
                #pragma unroll
                for (int nt = 0; nt < 3; ++nt)
                    pack4(&S[(16 * nt + j) * P + 16 * mt + 4 * g], na[mt][nt]);  // x'[field][dim]
            __syncthreads();
            #pragma unroll
            for (int nt = 0; nt < 3; ++nt)
                #pragma unroll
                for (int kt = 0; kt < 2; ++kt)
                    xf[nt][kt] = *(const s16x8*)&S[(j + 16 * nt) * P + 8 * g + 32 * kt];
        }
    }

    // ---------------- final linear + sigmoid ----------------
    float acc = 0.f;
    for (int f = 0; f < F; ++f) {
        uint u = ((uint)S[f * P + l]) << 16;
        acc += __builtin_bit_cast(float, u) * Wf[f * E + l];
    }
    #pragma unroll
    for (int off = 32; off > 0; off >>= 1) acc += __shfl_down(acc, off);
    if (l == 0) out[s] = 1.f / (1.f + __expf(-(acc + bfin[0])));
}

extern "C" void kernel_launch(void* const* d_in, const int* in_sizes, int n_in,
                              void* d_out, int out_size, void* d_ws, size_t ws_size,
                              hipStream_t stream) {
    ushort* wsb = (ushort*)d_ws;   // 61440 ushorts = 122880 B of scratch
    cvt_weights<<<240, 256, 0, stream>>>(
        (const float*)d_in[5], (const float*)d_in[6], (const float*)d_in[7],
        (const float*)d_in[8], (const float*)d_in[9], wsb);
    autoint_mfma<<<16384, 64, 0, stream>>>(
        (const float*)d_in[0], (const int*)d_in[1],
        (const float*)d_in[2], (const float*)d_in[3],
        (const float*)d_in[4], wsb,
        (const float*)d_in[10], (const float*)d_in[11],
        (float*)d_out);
}